// Round 1
// baseline (2323.396 us; speedup 1.0000x reference)
//
#include <hip/hip_runtime.h>
#include <math.h>

namespace {
constexpr int Bsz = 4;
constexpr int T   = 2048;
constexpr int C   = 1024;
constexpr int H   = 16;
constexpr int HD  = 64;

__device__ __forceinline__ float fc(const float4& v, int i) {
  return i == 0 ? v.x : i == 1 ? v.y : i == 2 ? v.z : v.w;
}

// C[M,N] = A[M,K] @ W[K,N], 128x128 tile per 256-thread block, BK=16.
// MODE 0: plain write to Cout. MODE 1: scatter qkv -> q/k/v [B,H,T,HD].
template <int MODE>
__global__ __launch_bounds__(256) void sgemm128(
    const float* __restrict__ A, const float* __restrict__ Wm,
    float* __restrict__ Cout, float* __restrict__ qp,
    float* __restrict__ kp, float* __restrict__ vp, int K, int N) {
  __shared__ __align__(16) float As[16][132];  // [k][m], padded
  __shared__ __align__(16) float Bs[16][132];  // [k][n], padded
  const int tid = threadIdx.x;
  const int tx = tid & 15, ty = tid >> 4;
  const int m0 = blockIdx.y * 128, n0 = blockIdx.x * 128;

  float4 acc[2][2][4];
#pragma unroll
  for (int qa = 0; qa < 2; ++qa)
#pragma unroll
    for (int qb = 0; qb < 2; ++qb)
#pragma unroll
      for (int i = 0; i < 4; ++i) acc[qa][qb][i] = make_float4(0.f, 0.f, 0.f, 0.f);

  for (int k0 = 0; k0 < K; k0 += 16) {
    // Stage A tile: 128 rows x 16 k. 512 float4 loads -> transpose into As[k][m].
#pragma unroll
    for (int i = 0; i < 2; ++i) {
      int e4 = tid + i * 256;          // 0..511
      int row = e4 >> 2, k4 = e4 & 3;  // 128 rows x 4 float4-chunks of k
      float4 va = *(const float4*)(A + (size_t)(m0 + row) * K + k0 + k4 * 4);
      As[k4 * 4 + 0][row] = va.x;
      As[k4 * 4 + 1][row] = va.y;
      As[k4 * 4 + 2][row] = va.z;
      As[k4 * 4 + 3][row] = va.w;
    }
    // Stage B tile: 16 k x 128 n, direct float4.
#pragma unroll
    for (int i = 0; i < 2; ++i) {
      int e4 = tid + i * 256;
      int kk = e4 >> 5, c4 = e4 & 31;
      *(float4*)&Bs[kk][c4 * 4] =
          *(const float4*)(Wm + (size_t)(k0 + kk) * N + n0 + c4 * 4);
    }
    __syncthreads();

#pragma unroll
    for (int kk = 0; kk < 16; ++kk) {
      float4 a0 = *(const float4*)&As[kk][ty * 4];
      float4 a1 = *(const float4*)&As[kk][64 + ty * 4];
      float4 b0 = *(const float4*)&Bs[kk][tx * 4];
      float4 b1 = *(const float4*)&Bs[kk][64 + tx * 4];
#pragma unroll
      for (int qa = 0; qa < 2; ++qa) {
        float4 av4 = qa ? a1 : a0;
#pragma unroll
        for (int i = 0; i < 4; ++i) {
          float av = fc(av4, i);
#pragma unroll
          for (int qb = 0; qb < 2; ++qb) {
            float4 bv = qb ? b1 : b0;
            acc[qa][qb][i].x += av * bv.x;
            acc[qa][qb][i].y += av * bv.y;
            acc[qa][qb][i].z += av * bv.z;
            acc[qa][qb][i].w += av * bv.w;
          }
        }
      }
    }
    __syncthreads();
  }

  // Epilogue
#pragma unroll
  for (int qa = 0; qa < 2; ++qa)
#pragma unroll
    for (int i = 0; i < 4; ++i) {
      int row = m0 + qa * 64 + ty * 4 + i;  // global M index (= b*T + t)
#pragma unroll
      for (int qb = 0; qb < 2; ++qb) {
        int col = n0 + qb * 64 + tx * 4;
        if (MODE == 0) {
          *(float4*)(Cout + (size_t)row * N + col) = acc[qa][qb][i];
        } else {
          int b = row >> 11;         // /T
          int t = row & (T - 1);
          int which = col >> 10;     // 0:q 1:k 2:v
          int rem = col & 1023;
          int h = rem >> 6, hd = rem & 63;
          float* dst = which == 0 ? qp : (which == 1 ? kp : vp);
          size_t off = (((size_t)(b * H + h)) * T + t) * (size_t)HD + hd;
          *(float4*)(dst + off) = acc[qa][qb][i];
        }
      }
    }
}

// RoPE in place on q and k, layout [B,H,T,HD]. One 32-lane group per (b,h,t).
__global__ __launch_bounds__(256) void rope_kernel(float* __restrict__ q,
                                                   float* __restrict__ k,
                                                   const int* __restrict__ idx) {
  const size_t g = (size_t)blockIdx.x * 8 + (threadIdx.x >> 5);  // bh*T + t
  const int lane = threadIdx.x & 31;
  const int t = (int)(g & (size_t)(T - 1));
  const int bh = (int)(g >> 11);
  const int b = bh >> 4;  // /H
  const int pos = idx[b * T + t];
  const float inv = 1.0f / powf(10000.0f, (float)lane * (1.0f / 32.0f));
  float sn, cs;
  sincosf((float)pos * inv, &sn, &cs);
  const size_t base = g * (size_t)HD;
  float x1 = q[base + lane], x2 = q[base + 32 + lane];
  q[base + lane]      = x1 * cs - x2 * sn;
  q[base + 32 + lane] = x1 * sn + x2 * cs;
  x1 = k[base + lane];
  x2 = k[base + 32 + lane];
  k[base + lane]      = x1 * cs - x2 * sn;
  k[base + 32 + lane] = x1 * sn + x2 * cs;
}

// Flash attention, fp32. Block = 256 threads handles 64 q rows of one (b,h).
// Thread (tx,ty) owns S/O 4x4 block: rows ty*4..+3, cols tx*4..+3.
__global__ __launch_bounds__(256) void flash_attn(
    const float* __restrict__ q, const float* __restrict__ k,
    const float* __restrict__ v, const int* __restrict__ idx,
    float* __restrict__ y) {
  __shared__ __align__(16) float Qs[64][68];   // [row][d]
  __shared__ __align__(16) float Kts[64][68];  // [d][krow] (K transposed)
  __shared__ __align__(16) float Vs[64][68];   // [krow][d]
  __shared__ __align__(16) float Ps[64][65];   // scores -> probs
  __shared__ float m_s[64], l_s[64], al_s[64];
  __shared__ int pq_s[64], pk_s[64];

  const int tid = threadIdx.x;
  const int tx = tid & 15, ty = tid >> 4;
  const int qt = blockIdx.x, h = blockIdx.y, b = blockIdx.z;
  const int q0 = qt * 64;
  const size_t bhoff = (size_t)(b * H + h) * (size_t)T * HD;
  const float* qb_ = q + bhoff;
  const float* kb_ = k + bhoff;
  const float* vb_ = v + bhoff;

  // Stage Q tile (64x64) as float4.
#pragma unroll
  for (int i = 0; i < 4; ++i) {
    int e4 = tid + i * 256;
    int r = e4 >> 4, d4 = e4 & 15;
    *(float4*)&Qs[r][d4 * 4] =
        *(const float4*)(qb_ + (size_t)(q0 + r) * HD + d4 * 4);
  }
  if (tid < 64) {
    m_s[tid] = -1e30f;
    l_s[tid] = 0.0f;
    pq_s[tid] = idx[b * T + q0 + tid];
  }
  float4 O[4];
#pragma unroll
  for (int i = 0; i < 4; ++i) O[i] = make_float4(0.f, 0.f, 0.f, 0.f);

  for (int kt = 0; kt <= qt; ++kt) {
    const int k0 = kt * 64;
    __syncthreads();  // previous iteration's readers done (also orders Q stage)

    // Stage K (transposed) and V tiles.
#pragma unroll
    for (int i = 0; i < 4; ++i) {
      int e4 = tid + i * 256;
      int r = e4 >> 4, d4 = e4 & 15;
      float4 kv = *(const float4*)(kb_ + (size_t)(k0 + r) * HD + d4 * 4);
      Kts[d4 * 4 + 0][r] = kv.x;
      Kts[d4 * 4 + 1][r] = kv.y;
      Kts[d4 * 4 + 2][r] = kv.z;
      Kts[d4 * 4 + 3][r] = kv.w;
      *(float4*)&Vs[r][d4 * 4] =
          *(const float4*)(vb_ + (size_t)(k0 + r) * HD + d4 * 4);
    }
    if (tid < 64) pk_s[tid] = idx[b * T + k0 + tid];
    __syncthreads();

    // S = Q K^T (4x4 per thread)
    float4 s4[4];
#pragma unroll
    for (int i = 0; i < 4; ++i) s4[i] = make_float4(0.f, 0.f, 0.f, 0.f);
#pragma unroll 8
    for (int d = 0; d < 64; ++d) {
      float4 bv = *(const float4*)&Kts[d][tx * 4];
#pragma unroll
      for (int i = 0; i < 4; ++i) {
        float av = Qs[ty * 4 + i][d];
        s4[i].x += av * bv.x;
        s4[i].y += av * bv.y;
        s4[i].z += av * bv.z;
        s4[i].w += av * bv.w;
      }
    }
    // scale + causal mask + store raw scores
#pragma unroll
    for (int i = 0; i < 4; ++i) {
      int pq = pq_s[ty * 4 + i];
      float sx = s4[i].x * 0.125f;
      if (pk_s[tx * 4 + 0] > pq) sx = -1e30f;
      Ps[ty * 4 + i][tx * 4 + 0] = sx;
      sx = s4[i].y * 0.125f;
      if (pk_s[tx * 4 + 1] > pq) sx = -1e30f;
      Ps[ty * 4 + i][tx * 4 + 1] = sx;
      sx = s4[i].z * 0.125f;
      if (pk_s[tx * 4 + 2] > pq) sx = -1e30f;
      Ps[ty * 4 + i][tx * 4 + 2] = sx;
      sx = s4[i].w * 0.125f;
      if (pk_s[tx * 4 + 3] > pq) sx = -1e30f;
      Ps[ty * 4 + i][tx * 4 + 3] = sx;
    }
    __syncthreads();

    // Online softmax per row (one thread per row).
    if (tid < 64) {
      float mold = m_s[tid];
      float mx = mold;
#pragma unroll 8
      for (int j = 0; j < 64; ++j) mx = fmaxf(mx, Ps[tid][j]);
      float alpha = __expf(mold - mx);
      float sum = 0.0f;
#pragma unroll 8
      for (int j = 0; j < 64; ++j) {
        float p = __expf(Ps[tid][j] - mx);
        Ps[tid][j] = p;
        sum += p;
      }
      l_s[tid] = l_s[tid] * alpha + sum;
      m_s[tid] = mx;
      al_s[tid] = alpha;
    }
    __syncthreads();

    // Rescale O, accumulate O += P V.
    float al[4];
#pragma unroll
    for (int i = 0; i < 4; ++i) al[i] = al_s[ty * 4 + i];
#pragma unroll
    for (int i = 0; i < 4; ++i) {
      O[i].x *= al[i];
      O[i].y *= al[i];
      O[i].z *= al[i];
      O[i].w *= al[i];
    }
#pragma unroll 8
    for (int kk = 0; kk < 64; ++kk) {
      float4 vv = *(const float4*)&Vs[kk][tx * 4];
#pragma unroll
      for (int i = 0; i < 4; ++i) {
        float p = Ps[ty * 4 + i][kk];
        O[i].x += p * vv.x;
        O[i].y += p * vv.y;
        O[i].z += p * vv.z;
        O[i].w += p * vv.w;
      }
    }
  }

  // Write y[b, t, h*HD + d] = O / l
#pragma unroll
  for (int i = 0; i < 4; ++i) {
    float rl = 1.0f / l_s[ty * 4 + i];
    float4 o = make_float4(O[i].x * rl, O[i].y * rl, O[i].z * rl, O[i].w * rl);
    *(float4*)(y + ((size_t)b * T + q0 + ty * 4 + i) * (size_t)C + h * HD +
               tx * 4) = o;
  }
}

}  // namespace

extern "C" void kernel_launch(void* const* d_in, const int* in_sizes, int n_in,
                              void* d_out, int out_size, void* d_ws,
                              size_t ws_size, hipStream_t stream) {
  const float* x      = (const float*)d_in[0];
  const float* W_attn = (const float*)d_in[1];
  const float* W_proj = (const float*)d_in[2];
  const int* indices  = (const int*)d_in[3];
  float* out = (float*)d_out;

  const size_t nqkv = (size_t)Bsz * H * T * HD;  // 8,388,608 elements
  float* qp = (float*)d_ws;
  float* kp = qp + nqkv;
  float* vp = kp + nqkv;
  float* yp = vp + nqkv;

  // qkv = x @ W_attn, scattered to q/k/v [B,H,T,HD]
  sgemm128<1><<<dim3(3 * C / 128, Bsz * T / 128), 256, 0, stream>>>(
      x, W_attn, nullptr, qp, kp, vp, C, 3 * C);
  // RoPE on q, k
  rope_kernel<<<(Bsz * H * T) / 8, 256, 0, stream>>>(qp, kp, indices);
  // attention -> y [B,T,C]
  flash_attn<<<dim3(T / 64, H, Bsz), 256, 0, stream>>>(qp, kp, vp, indices, yp);
  // out = y @ W_proj
  sgemm128<0><<<dim3(C / 128, Bsz * T / 128), 256, 0, stream>>>(
      yp, W_proj, out, nullptr, nullptr, nullptr, C, C);
}

// Round 2
// 466.146 us; speedup vs baseline: 4.9843x; 4.9843x over previous
//
#include <hip/hip_runtime.h>
#include <math.h>

namespace {
constexpr int Bsz = 4;
constexpr int T   = 2048;
constexpr int C   = 1024;
constexpr int H   = 16;
constexpr int HD  = 64;

typedef short bf16x8 __attribute__((ext_vector_type(8)));
typedef float f32x4  __attribute__((ext_vector_type(4)));

__device__ __forceinline__ unsigned short f2bf(float f) {
  unsigned int u = __builtin_bit_cast(unsigned int, f);
  u += 0x7FFFu + ((u >> 16) & 1u);
  return (unsigned short)(u >> 16);
}
__device__ __forceinline__ float bf2f(unsigned short s) {
  unsigned int u = ((unsigned int)s) << 16;
  return __builtin_bit_cast(float, u);
}

// ---------------- fp32 -> bf16 (same layout) ----------------
__global__ __launch_bounds__(256) void f32_to_bf16_kernel(
    const float* __restrict__ in, unsigned short* __restrict__ out, int n4) {
  int i = blockIdx.x * 256 + threadIdx.x;
  if (i < n4) {
    float4 v = ((const float4*)in)[i];
    ushort4 o;
    o.x = f2bf(v.x); o.y = f2bf(v.y); o.z = f2bf(v.z); o.w = f2bf(v.w);
    ((ushort4*)out)[i] = o;
  }
}

// ---------------- W [K,N] fp32 -> Wt [N,K] bf16 ----------------
__global__ __launch_bounds__(256) void transpose_bf16_kernel(
    const float* __restrict__ W, unsigned short* __restrict__ Wt, int K, int N) {
  __shared__ float tile[32][33];
  const int n0 = blockIdx.x * 32, k0 = blockIdx.y * 32;
  const int r = threadIdx.x >> 3, c4 = threadIdx.x & 7;
  float4 v = *(const float4*)(W + (size_t)(k0 + r) * N + n0 + c4 * 4);
  tile[r][c4 * 4 + 0] = v.x;
  tile[r][c4 * 4 + 1] = v.y;
  tile[r][c4 * 4 + 2] = v.z;
  tile[r][c4 * 4 + 3] = v.w;
  __syncthreads();
  ushort4 o;
  o.x = f2bf(tile[c4 * 4 + 0][r]);
  o.y = f2bf(tile[c4 * 4 + 1][r]);
  o.z = f2bf(tile[c4 * 4 + 2][r]);
  o.w = f2bf(tile[c4 * 4 + 3][r]);
  *(ushort4*)(Wt + (size_t)(n0 + r) * K + k0 + c4 * 4) = o;
}

// ---------------- bf16 MFMA GEMM: C[M,N] = A[M,K] @ Bt[N,K]^T ----------------
// 128x128 tile, 4 waves in 2x2, BK=32. MODE 0: fp32 C. MODE 1: bf16 qkv scatter.
template <int MODE>
__global__ __launch_bounds__(256) void gemm_bt(
    const unsigned short* __restrict__ A, const unsigned short* __restrict__ Bt,
    float* __restrict__ Cout, unsigned short* __restrict__ qp,
    unsigned short* __restrict__ kp, unsigned short* __restrict__ vp,
    int M, int N, int K) {
  __shared__ __align__(16) unsigned short As[128][40];  // stride 40 bf16 = 80B
  __shared__ __align__(16) unsigned short Bs[128][40];
  const int tid = threadIdx.x;
  const int lane = tid & 63, w = tid >> 6;
  const int wr = w & 1, wc = w >> 1;
  const int l15 = lane & 15, quad = lane >> 4;
  const int m0 = blockIdx.y * 128, n0 = blockIdx.x * 128;
  const int ar0 = tid >> 2, ac0 = (tid & 3) * 8;  // 64 rows x 4 chunks of 8 bf16

  f32x4 acc[4][4] = {};

  for (int k0 = 0; k0 < K; k0 += 32) {
    __syncthreads();
    uint4 va1 = *(const uint4*)(A + (size_t)(m0 + ar0) * K + k0 + ac0);
    uint4 va2 = *(const uint4*)(A + (size_t)(m0 + 64 + ar0) * K + k0 + ac0);
    uint4 vb1 = *(const uint4*)(Bt + (size_t)(n0 + ar0) * K + k0 + ac0);
    uint4 vb2 = *(const uint4*)(Bt + (size_t)(n0 + 64 + ar0) * K + k0 + ac0);
    *(uint4*)&As[ar0][ac0] = va1;
    *(uint4*)&As[64 + ar0][ac0] = va2;
    *(uint4*)&Bs[ar0][ac0] = vb1;
    *(uint4*)&Bs[64 + ar0][ac0] = vb2;
    __syncthreads();

    bf16x8 af[4], bfr[4];
#pragma unroll
    for (int mf = 0; mf < 4; ++mf)
      af[mf] = *(const bf16x8*)&As[wr * 64 + mf * 16 + l15][quad * 8];
#pragma unroll
    for (int nf = 0; nf < 4; ++nf)
      bfr[nf] = *(const bf16x8*)&Bs[wc * 64 + nf * 16 + l15][quad * 8];
#pragma unroll
    for (int mf = 0; mf < 4; ++mf)
#pragma unroll
      for (int nf = 0; nf < 4; ++nf)
        acc[mf][nf] = __builtin_amdgcn_mfma_f32_16x16x32_bf16(
            af[mf], bfr[nf], acc[mf][nf], 0, 0, 0);
  }

#pragma unroll
  for (int mf = 0; mf < 4; ++mf) {
#pragma unroll
    for (int r = 0; r < 4; ++r) {
      const int row = m0 + wr * 64 + mf * 16 + quad * 4 + r;
#pragma unroll
      for (int nf = 0; nf < 4; ++nf) {
        const int col = n0 + wc * 64 + nf * 16 + l15;
        const float v = acc[mf][nf][r];
        if (MODE == 0) {
          Cout[(size_t)row * N + col] = v;
        } else {
          const int b = row >> 11, t = row & (T - 1);
          const int which = col >> 10, rem = col & (C - 1);
          const int h = rem >> 6, hd = rem & 63;
          unsigned short* dst = which == 0 ? qp : (which == 1 ? kp : vp);
          dst[(((size_t)(b * H + h)) * T + t) * HD + hd] = f2bf(v);
        }
      }
    }
  }
}

// ---------------- RoPE in place on bf16 q,k [B,H,T,HD] ----------------
__global__ __launch_bounds__(256) void rope_bf16(unsigned short* __restrict__ q,
                                                 unsigned short* __restrict__ k,
                                                 const int* __restrict__ idx) {
  const size_t g = (size_t)blockIdx.x * 8 + (threadIdx.x >> 5);  // bh*T + t
  const int lane = threadIdx.x & 31;
  const int t = (int)(g & (size_t)(T - 1));
  const int bh = (int)(g >> 11);
  const int b = bh >> 4;
  const int pos = idx[b * T + t];
  const float inv = 1.0f / powf(10000.0f, (float)lane * (1.0f / 32.0f));
  float sn, cs;
  sincosf((float)pos * inv, &sn, &cs);
  const size_t base = g * (size_t)HD;
  float x1 = bf2f(q[base + lane]), x2 = bf2f(q[base + 32 + lane]);
  q[base + lane]      = f2bf(x1 * cs - x2 * sn);
  q[base + 32 + lane] = f2bf(x1 * sn + x2 * cs);
  x1 = bf2f(k[base + lane]);
  x2 = bf2f(k[base + 32 + lane]);
  k[base + lane]      = f2bf(x1 * cs - x2 * sn);
  k[base + 32 + lane] = f2bf(x1 * sn + x2 * cs);
}

// ---------------- MFMA flash attention ----------------
// Block: 256 threads = 4 waves; 64 Q rows (wave w owns rows w*16..+15).
// K/V tiles of 64 keys. Vt stored transposed with block-rotation swizzle.
__global__ __launch_bounds__(256) void flash_attn_mfma(
    const unsigned short* __restrict__ q, const unsigned short* __restrict__ k,
    const unsigned short* __restrict__ v, const int* __restrict__ idx,
    unsigned short* __restrict__ y) {
  __shared__ __align__(16) unsigned short Qs[64][72];  // [qrow][d]
  __shared__ __align__(16) unsigned short Ks[64][72];  // [key][d]
  __shared__ __align__(16) unsigned short Vt[64][72];  // [d][key] swizzled
  __shared__ __align__(16) unsigned short Ps[64][72];  // [qrow][key]
  __shared__ int pk_s[64];

  const int tid = threadIdx.x;
  const int lane = tid & 63, w = tid >> 6;
  const int l15 = lane & 15, quad = lane >> 4;
  const int qt = blockIdx.x, h = blockIdx.y, b = blockIdx.z;
  const int q0 = qt * 64;
  const size_t bhoff = ((size_t)(b * H + h)) * (size_t)T * HD;
  const unsigned short* qg = q + bhoff;
  const unsigned short* kg = k + bhoff;
  const unsigned short* vg = v + bhoff;

  // chunk decomposition: 64 rows x 8 chunks(16B) = 512, 2 per thread
  const int r1 = tid >> 3, c1 = tid & 7;
  const int e2 = tid + 256;
  const int r2 = e2 >> 3, c2 = e2 & 7;

  // stage Q
  {
    uint4 v1 = *(const uint4*)(qg + (size_t)(q0 + r1) * HD + c1 * 8);
    uint4 v2 = *(const uint4*)(qg + (size_t)(q0 + r2) * HD + c2 * 8);
    *(uint4*)&Qs[r1][c1 * 8] = v1;
    *(uint4*)&Qs[r2][c2 * 8] = v2;
  }

  int pq[4];
#pragma unroll
  for (int r = 0; r < 4; ++r) pq[r] = idx[b * T + q0 + w * 16 + quad * 4 + r];

  float m_prev[4], l_run[4];
#pragma unroll
  for (int r = 0; r < 4; ++r) { m_prev[r] = -1e30f; l_run[r] = 0.0f; }
  f32x4 Oa[4] = {};

  for (int kt = 0; kt <= qt; ++kt) {
    const int k0 = kt * 64;
    __syncthreads();
    // stage K (row-major) and V (transposed+swizzled)
    {
      uint4 kv1 = *(const uint4*)(kg + (size_t)(k0 + r1) * HD + c1 * 8);
      uint4 kv2 = *(const uint4*)(kg + (size_t)(k0 + r2) * HD + c2 * 8);
      *(uint4*)&Ks[r1][c1 * 8] = kv1;
      *(uint4*)&Ks[r2][c2 * 8] = kv2;
      uint4 vv1 = *(const uint4*)(vg + (size_t)(k0 + r1) * HD + c1 * 8);
      uint4 vv2 = *(const uint4*)(vg + (size_t)(k0 + r2) * HD + c2 * 8);
      unsigned int u1[4] = {vv1.x, vv1.y, vv1.z, vv1.w};
      unsigned int u2[4] = {vv2.x, vv2.y, vv2.z, vv2.w};
      // element j of chunk (rK,cK) is V[key=rK][d=cK*8+j] -> Vt[d][swz(key,d)]
#pragma unroll
      for (int j = 0; j < 4; ++j) {
        int d1a = c1 * 8 + 2 * j, d1b = d1a + 1;
        int col1a = ((((r1 >> 3) + (d1a >> 3)) & 7) << 3) | (r1 & 7);
        int col1b = ((((r1 >> 3) + (d1b >> 3)) & 7) << 3) | (r1 & 7);
        Vt[d1a][col1a] = (unsigned short)(u1[j] & 0xFFFFu);
        Vt[d1b][col1b] = (unsigned short)(u1[j] >> 16);
        int d2a = c2 * 8 + 2 * j, d2b = d2a + 1;
        int col2a = ((((r2 >> 3) + (d2a >> 3)) & 7) << 3) | (r2 & 7);
        int col2b = ((((r2 >> 3) + (d2b >> 3)) & 7) << 3) | (r2 & 7);
        Vt[d2a][col2a] = (unsigned short)(u2[j] & 0xFFFFu);
        Vt[d2b][col2b] = (unsigned short)(u2[j] >> 16);
      }
      if (tid < 64) pk_s[tid] = idx[b * T + k0 + tid];
    }
    __syncthreads();

    // S = Q K^T for this wave's 16 rows x 64 keys
    bf16x8 aq0 = *(const bf16x8*)&Qs[w * 16 + l15][quad * 8];
    bf16x8 aq1 = *(const bf16x8*)&Qs[w * 16 + l15][32 + quad * 8];
    f32x4 S[4];
#pragma unroll
    for (int nf = 0; nf < 4; ++nf) {
      bf16x8 b0 = *(const bf16x8*)&Ks[nf * 16 + l15][quad * 8];
      bf16x8 b1 = *(const bf16x8*)&Ks[nf * 16 + l15][32 + quad * 8];
      f32x4 s = {};
      s = __builtin_amdgcn_mfma_f32_16x16x32_bf16(aq0, b0, s, 0, 0, 0);
      s = __builtin_amdgcn_mfma_f32_16x16x32_bf16(aq1, b1, s, 0, 0, 0);
      S[nf] = s;
    }

    // mask + online softmax (C-layout: col = nf*16+l15, row = quad*4+r)
    float sv[4][4];
    int pk[4];
#pragma unroll
    for (int nf = 0; nf < 4; ++nf) pk[nf] = pk_s[nf * 16 + l15];
#pragma unroll
    for (int nf = 0; nf < 4; ++nf)
#pragma unroll
      for (int r = 0; r < 4; ++r) {
        float x = S[nf][r] * 0.125f;
        if (pk[nf] > pq[r]) x = -1e30f;
        sv[nf][r] = x;
      }
    float alpha[4];
#pragma unroll
    for (int r = 0; r < 4; ++r) {
      float mx = fmaxf(fmaxf(sv[0][r], sv[1][r]), fmaxf(sv[2][r], sv[3][r]));
#pragma unroll
      for (int off = 1; off < 16; off <<= 1) mx = fmaxf(mx, __shfl_xor(mx, off));
      float mn = fmaxf(m_prev[r], mx);
      alpha[r] = __expf(m_prev[r] - mn);
      m_prev[r] = mn;
      float s = 0.0f;
#pragma unroll
      for (int nf = 0; nf < 4; ++nf) {
        float p = __expf(sv[nf][r] - mn);
        sv[nf][r] = p;
        s += p;
      }
#pragma unroll
      for (int off = 1; off < 16; off <<= 1) s += __shfl_xor(s, off);
      l_run[r] = l_run[r] * alpha[r] + s;
    }
    // write P (wave-private rows) and rescale O
#pragma unroll
    for (int nf = 0; nf < 4; ++nf)
#pragma unroll
      for (int r = 0; r < 4; ++r)
        Ps[w * 16 + quad * 4 + r][nf * 16 + l15] = f2bf(sv[nf][r]);
#pragma unroll
    for (int nf = 0; nf < 4; ++nf)
#pragma unroll
      for (int r = 0; r < 4; ++r) Oa[nf][r] *= alpha[r];

    // O += P V  (A = Ps rows, B = Vt rows with swizzled key blocks)
    bf16x8 p0 = *(const bf16x8*)&Ps[w * 16 + l15][quad * 8];
    bf16x8 p1 = *(const bf16x8*)&Ps[w * 16 + l15][32 + quad * 8];
#pragma unroll
    for (int nf = 0; nf < 4; ++nf) {
      const int d = nf * 16 + l15;
      const int kb0 = (quad + (d >> 3)) & 7;        // kc=0 block
      const int kb1 = (4 + quad + (d >> 3)) & 7;    // kc=1 block
      bf16x8 v0 = *(const bf16x8*)&Vt[d][kb0 * 8];
      bf16x8 v1 = *(const bf16x8*)&Vt[d][kb1 * 8];
      Oa[nf] = __builtin_amdgcn_mfma_f32_16x16x32_bf16(p0, v0, Oa[nf], 0, 0, 0);
      Oa[nf] = __builtin_amdgcn_mfma_f32_16x16x32_bf16(p1, v1, Oa[nf], 0, 0, 0);
    }
  }

  // write y bf16 [B,T,C]
#pragma unroll
  for (int r = 0; r < 4; ++r) {
    const float rl = 1.0f / l_run[r];
    const int row = q0 + w * 16 + quad * 4 + r;
    const size_t base = ((size_t)b * T + row) * (size_t)C + h * HD;
#pragma unroll
    for (int nf = 0; nf < 4; ++nf) y[base + nf * 16 + l15] = f2bf(Oa[nf][r] * rl);
  }
}

}  // namespace

extern "C" void kernel_launch(void* const* d_in, const int* in_sizes, int n_in,
                              void* d_out, int out_size, void* d_ws,
                              size_t ws_size, hipStream_t stream) {
  const float* x      = (const float*)d_in[0];
  const float* W_attn = (const float*)d_in[1];
  const float* W_proj = (const float*)d_in[2];
  const int* indices  = (const int*)d_in[3];
  float* out = (float*)d_out;

  const size_t nM = (size_t)Bsz * T * C;  // 8M elements
  unsigned short* xb  = (unsigned short*)d_ws;
  unsigned short* wat = xb + nM;                       // [3C, C] transposed
  unsigned short* wpt = wat + (size_t)3 * C * C;       // [C, C] transposed
  unsigned short* qp  = wpt + (size_t)C * C;
  unsigned short* kp  = qp + nM;
  unsigned short* vp  = kp + nM;
  unsigned short* yb  = vp + nM;

  // x -> bf16
  f32_to_bf16_kernel<<<(int)(nM / 4 / 256), 256, 0, stream>>>(x, xb, (int)(nM / 4));
  // W_attn [C,3C] -> wat [3C,C]; W_proj [C,C] -> wpt [C,C]
  transpose_bf16_kernel<<<dim3(3 * C / 32, C / 32), 256, 0, stream>>>(W_attn, wat, C, 3 * C);
  transpose_bf16_kernel<<<dim3(C / 32, C / 32), 256, 0, stream>>>(W_proj, wpt, C, C);
  // qkv = x @ W_attn  (scatter bf16 q/k/v [B,H,T,HD])
  gemm_bt<1><<<dim3(3 * C / 128, Bsz * T / 128), 256, 0, stream>>>(
      xb, wat, nullptr, qp, kp, vp, Bsz * T, 3 * C, C);
  // RoPE
  rope_bf16<<<(Bsz * H * T) / 8, 256, 0, stream>>>(qp, kp, indices);
  // attention -> yb bf16 [B,T,C]
  flash_attn_mfma<<<dim3(T / 64, H, Bsz), 256, 0, stream>>>(qp, kp, vp, indices, yb);
  // out = y @ W_proj (fp32 out)
  gemm_bt<0><<<dim3(C / 128, Bsz * T / 128), 256, 0, stream>>>(
      yb, wpt, out, nullptr, nullptr, nullptr, Bsz * T, C, C);
}

// Round 3
// 383.705 us; speedup vs baseline: 6.0552x; 1.2149x over previous
//
#include <hip/hip_runtime.h>
#include <math.h>

namespace {
constexpr int Bsz = 4;
constexpr int T   = 2048;
constexpr int C   = 1024;
constexpr int H   = 16;
constexpr int HD  = 64;

typedef short bf16x8 __attribute__((ext_vector_type(8)));
typedef float f32x4  __attribute__((ext_vector_type(4)));

#if defined(__has_builtin)
#if __has_builtin(__builtin_amdgcn_global_load_lds)
#define HAVE_GLL 1
typedef __attribute__((address_space(3))) unsigned int lds_u32_t;
typedef __attribute__((address_space(1))) unsigned int g_u32_t;
#define GLL16(gp, lp)                                                        \
  __builtin_amdgcn_global_load_lds((const g_u32_t*)(gp), (lds_u32_t*)(lp),   \
                                   16, 0, 0)
#endif
#endif

__device__ __forceinline__ unsigned short f2bf(float f) {
  unsigned int u = __builtin_bit_cast(unsigned int, f);
  u += 0x7FFFu + ((u >> 16) & 1u);
  return (unsigned short)(u >> 16);
}
__device__ __forceinline__ float bf2f(unsigned short s) {
  unsigned int u = ((unsigned int)s) << 16;
  return __builtin_bit_cast(float, u);
}

// ---------------- fp32 -> bf16 (same layout) ----------------
__global__ __launch_bounds__(256) void f32_to_bf16_kernel(
    const float* __restrict__ in, unsigned short* __restrict__ out, int n4) {
  int i = blockIdx.x * 256 + threadIdx.x;
  if (i < n4) {
    float4 v = ((const float4*)in)[i];
    ushort4 o;
    o.x = f2bf(v.x); o.y = f2bf(v.y); o.z = f2bf(v.z); o.w = f2bf(v.w);
    ((ushort4*)out)[i] = o;
  }
}

// ---------------- W [K,N] fp32 -> Wt [N,K] bf16 ----------------
__global__ __launch_bounds__(256) void transpose_bf16_kernel(
    const float* __restrict__ W, unsigned short* __restrict__ Wt, int K, int N) {
  __shared__ float tile[32][33];
  const int n0 = blockIdx.x * 32, k0 = blockIdx.y * 32;
  const int r = threadIdx.x >> 3, c4 = threadIdx.x & 7;
  float4 v = *(const float4*)(W + (size_t)(k0 + r) * N + n0 + c4 * 4);
  tile[r][c4 * 4 + 0] = v.x;
  tile[r][c4 * 4 + 1] = v.y;
  tile[r][c4 * 4 + 2] = v.z;
  tile[r][c4 * 4 + 3] = v.w;
  __syncthreads();
  ushort4 o;
  o.x = f2bf(tile[c4 * 4 + 0][r]);
  o.y = f2bf(tile[c4 * 4 + 1][r]);
  o.z = f2bf(tile[c4 * 4 + 2][r]);
  o.w = f2bf(tile[c4 * 4 + 3][r]);
  *(ushort4*)(Wt + (size_t)(n0 + r) * K + k0 + c4 * 4) = o;
}

// ---------------- bf16 MFMA GEMM: C[M,N] = A[M,K] @ Bt[N,K]^T ----------------
// 128x128 tile, 4 waves 2x2, BK=32, global_load_lds staging (m97 pattern).
// MODE 0: fp32 C. MODE 1: scatter q/k [B,H,T,HD] bf16 + v transposed [B,H,HD,T].
template <int MODE>
__global__ __launch_bounds__(256) void gemm_bt(
    const unsigned short* __restrict__ A, const unsigned short* __restrict__ Bt,
    float* __restrict__ Cout, unsigned short* __restrict__ qp,
    unsigned short* __restrict__ kp, unsigned short* __restrict__ vp,
    int M, int N, int K) {
  __shared__ __align__(16) unsigned short As[128 * 32];  // unpadded, 64B rows
  __shared__ __align__(16) unsigned short Bs[128 * 32];
  const int tid = threadIdx.x;
  const int lane = tid & 63, w = tid >> 6;
  const int wr = w & 1, wc = w >> 1;
  const int l15 = lane & 15, quad = lane >> 4;
  const int m0 = blockIdx.y * 128, n0 = blockIdx.x * 128;

  // staging coords: wave w covers rows w*32 .. w*32+31 (two 16-row chunks)
  const int srow = lane >> 2;        // 0..15
  const int schunk = (lane & 3) * 8; // bf16 offset within 64B row
  const unsigned short* gA = A + (size_t)(m0 + w * 32 + srow) * K + schunk;
  const unsigned short* gB = Bt + (size_t)(n0 + w * 32 + srow) * K + schunk;
  unsigned short* lA0 = &As[(w * 32) * 32 + lane * 8];
  unsigned short* lA1 = &As[(w * 32 + 16) * 32 + lane * 8];
  unsigned short* lB0 = &Bs[(w * 32) * 32 + lane * 8];
  unsigned short* lB1 = &Bs[(w * 32 + 16) * 32 + lane * 8];

  f32x4 acc[4][4] = {};

  for (int k0 = 0; k0 < K; k0 += 32) {
    __syncthreads();
#ifdef HAVE_GLL
    GLL16(gA + k0, lA0);
    GLL16(gA + (size_t)16 * K + k0, lA1);
    GLL16(gB + k0, lB0);
    GLL16(gB + (size_t)16 * K + k0, lB1);
#else
    *(uint4*)lA0 = *(const uint4*)(gA + k0);
    *(uint4*)lA1 = *(const uint4*)(gA + (size_t)16 * K + k0);
    *(uint4*)lB0 = *(const uint4*)(gB + k0);
    *(uint4*)lB1 = *(const uint4*)(gB + (size_t)16 * K + k0);
#endif
    __syncthreads();

    bf16x8 af[4], bfr[4];
#pragma unroll
    for (int mf = 0; mf < 4; ++mf)
      af[mf] = *(const bf16x8*)&As[(wr * 64 + mf * 16 + l15) * 32 + quad * 8];
#pragma unroll
    for (int nf = 0; nf < 4; ++nf)
      bfr[nf] = *(const bf16x8*)&Bs[(wc * 64 + nf * 16 + l15) * 32 + quad * 8];
#pragma unroll
    for (int mf = 0; mf < 4; ++mf)
#pragma unroll
      for (int nf = 0; nf < 4; ++nf)
        acc[mf][nf] = __builtin_amdgcn_mfma_f32_16x16x32_bf16(
            af[mf], bfr[nf], acc[mf][nf], 0, 0, 0);
  }

#pragma unroll
  for (int mf = 0; mf < 4; ++mf) {
    const int row0 = m0 + wr * 64 + mf * 16 + quad * 4;
#pragma unroll
    for (int nf = 0; nf < 4; ++nf) {
      if (MODE == 0) {
#pragma unroll
        for (int r = 0; r < 4; ++r) {
          const int col = n0 + wc * 64 + nf * 16 + l15;
          Cout[(size_t)(row0 + r) * N + col] = acc[mf][nf][r];
        }
      } else {
        const int col = n0 + wc * 64 + nf * 16 + l15;
        const int which = col >> 10;          // wave-uniform (16-col chunks)
        const int rem = col & (C - 1);
        const int h = rem >> 6, hd = rem & 63;
        const int b = row0 >> 11, t0 = row0 & (T - 1);
        if (which == 2) {
          // V transposed: [B,H,HD,T], 4 consecutive t -> b64 store
          ushort4 pv;
          pv.x = f2bf(acc[mf][nf][0]);
          pv.y = f2bf(acc[mf][nf][1]);
          pv.z = f2bf(acc[mf][nf][2]);
          pv.w = f2bf(acc[mf][nf][3]);
          *(ushort4*)(vp + (((size_t)(b * H + h)) * HD + hd) * T + t0) = pv;
        } else {
          unsigned short* dst = which == 0 ? qp : kp;
#pragma unroll
          for (int r = 0; r < 4; ++r)
            dst[(((size_t)(b * H + h)) * T + t0 + r) * HD + hd] =
                f2bf(acc[mf][nf][r]);
        }
      }
    }
  }
}

// ---------------- RoPE in place on bf16 q,k [B,H,T,HD] ----------------
__global__ __launch_bounds__(256) void rope_bf16(unsigned short* __restrict__ q,
                                                 unsigned short* __restrict__ k,
                                                 const int* __restrict__ idx) {
  const size_t g = (size_t)blockIdx.x * 8 + (threadIdx.x >> 5);  // bh*T + t
  const int lane = threadIdx.x & 31;
  const int t = (int)(g & (size_t)(T - 1));
  const int bh = (int)(g >> 11);
  const int b = bh >> 4;
  const int pos = idx[b * T + t];
  const float inv = 1.0f / powf(10000.0f, (float)lane * (1.0f / 32.0f));
  float sn, cs;
  sincosf((float)pos * inv, &sn, &cs);
  const size_t base = g * (size_t)HD;
  float x1 = bf2f(q[base + lane]), x2 = bf2f(q[base + 32 + lane]);
  q[base + lane]      = f2bf(x1 * cs - x2 * sn);
  q[base + 32 + lane] = f2bf(x1 * sn + x2 * cs);
  x1 = bf2f(k[base + lane]);
  x2 = bf2f(k[base + 32 + lane]);
  k[base + lane]      = f2bf(x1 * cs - x2 * sn);
  k[base + 32 + lane] = f2bf(x1 * sn + x2 * cs);
}

// ---------------- MFMA flash attention, S^T formulation ----------------
// Block: 4 waves; wave w owns 16 q-rows (w*16..+15). Q-tile 64, K-tile 64.
// S^T = K·Q^T -> C-layout: lane l15 = qrow, regs = keys -> softmax rows
// reduce in-register + 2 shfls. V pre-transposed in global [B,H,HD,T].
__global__ __launch_bounds__(256) void flash_attn_mfma(
    const unsigned short* __restrict__ q, const unsigned short* __restrict__ k,
    const unsigned short* __restrict__ vt, const int* __restrict__ idx,
    unsigned short* __restrict__ y) {
  __shared__ __align__(16) unsigned short Qs[64][72];   // [qrow][d]
  __shared__ __align__(16) unsigned short Ks[64][72];   // [key][d]
  __shared__ __align__(16) unsigned short Vts[64][72];  // [d][key]
  __shared__ __align__(16) unsigned short Pq[64][72];   // [qrow][key]
  __shared__ int pk_s[64];

  const int tid = threadIdx.x;
  const int lane = tid & 63, w = tid >> 6;
  const int l15 = lane & 15, quad = lane >> 4;
  const int qt = blockIdx.x, h = blockIdx.y, b = blockIdx.z;
  const int q0 = qt * 64;
  const size_t bh = (size_t)(b * H + h);
  const unsigned short* qg = q + bh * T * HD;
  const unsigned short* kg = k + bh * T * HD;
  const unsigned short* vg = vt + bh * HD * T;

  const int r1 = tid >> 3, c1 = tid & 7;       // 32 rows x 8 chunks
  const int r2 = r1 + 32, c2 = c1;

  // stage Q
  *(uint4*)&Qs[r1][c1 * 8] = *(const uint4*)(qg + (size_t)(q0 + r1) * HD + c1 * 8);
  *(uint4*)&Qs[r2][c2 * 8] = *(const uint4*)(qg + (size_t)(q0 + r2) * HD + c2 * 8);
  __syncthreads();
  const bf16x8 bq0 = *(const bf16x8*)&Qs[w * 16 + l15][quad * 8];
  const bf16x8 bq1 = *(const bf16x8*)&Qs[w * 16 + l15][32 + quad * 8];

  const int pq = idx[b * T + q0 + w * 16 + l15];  // this lane's q position
  float m_prev = -1e30f, l_run = 0.0f;
  f32x4 Oa[4] = {};

  for (int kt = 0; kt <= qt; ++kt) {
    const int k0 = kt * 64;
    __syncthreads();  // prior reads of Ks/Vts complete
    *(uint4*)&Ks[r1][c1 * 8] = *(const uint4*)(kg + (size_t)(k0 + r1) * HD + c1 * 8);
    *(uint4*)&Ks[r2][c2 * 8] = *(const uint4*)(kg + (size_t)(k0 + r2) * HD + c2 * 8);
    *(uint4*)&Vts[r1][c1 * 8] = *(const uint4*)(vg + (size_t)r1 * T + k0 + c1 * 8);
    *(uint4*)&Vts[r2][c2 * 8] = *(const uint4*)(vg + (size_t)r2 * T + k0 + c2 * 8);
    if (tid < 64) pk_s[tid] = idx[b * T + k0 + tid];
    __syncthreads();

    // S^T[key][qrow]: A = K rows (m=key), B = Q rows (n=qrow)
    f32x4 St[4];
#pragma unroll
    for (int nf = 0; nf < 4; ++nf) {
      bf16x8 ak0 = *(const bf16x8*)&Ks[nf * 16 + l15][quad * 8];
      bf16x8 ak1 = *(const bf16x8*)&Ks[nf * 16 + l15][32 + quad * 8];
      f32x4 s = {};
      s = __builtin_amdgcn_mfma_f32_16x16x32_bf16(ak0, bq0, s, 0, 0, 0);
      s = __builtin_amdgcn_mfma_f32_16x16x32_bf16(ak1, bq1, s, 0, 0, 0);
      St[nf] = s;
    }

    // mask + scale; reg r of tile nf = key nf*16+quad*4+r, lane l15 = qrow
    float sv[4][4];
#pragma unroll
    for (int nf = 0; nf < 4; ++nf) {
      const int4 pk4 = *(const int4*)&pk_s[nf * 16 + quad * 4];
      sv[nf][0] = (pk4.x > pq) ? -1e30f : St[nf][0] * 0.125f;
      sv[nf][1] = (pk4.y > pq) ? -1e30f : St[nf][1] * 0.125f;
      sv[nf][2] = (pk4.z > pq) ? -1e30f : St[nf][2] * 0.125f;
      sv[nf][3] = (pk4.w > pq) ? -1e30f : St[nf][3] * 0.125f;
    }
    // row max: in-lane over 16 + 2 shfls across quads
    float mx = sv[0][0];
#pragma unroll
    for (int nf = 0; nf < 4; ++nf)
#pragma unroll
      for (int r = 0; r < 4; ++r) mx = fmaxf(mx, sv[nf][r]);
    mx = fmaxf(mx, __shfl_xor(mx, 16));
    mx = fmaxf(mx, __shfl_xor(mx, 32));
    const float mn = fmaxf(m_prev, mx);
    const float alpha = __expf(m_prev - mn);
    m_prev = mn;
    float sum = 0.0f;
#pragma unroll
    for (int nf = 0; nf < 4; ++nf)
#pragma unroll
      for (int r = 0; r < 4; ++r) {
        float p = __expf(sv[nf][r] - mn);
        sv[nf][r] = p;
        sum += p;
      }
    sum += __shfl_xor(sum, 16);
    sum += __shfl_xor(sum, 32);
    l_run = l_run * alpha + sum;

    // write P[qrow][key]: 4 consecutive keys per reg group -> b64 stores
#pragma unroll
    for (int nf = 0; nf < 4; ++nf) {
      ushort4 pw;
      pw.x = f2bf(sv[nf][0]);
      pw.y = f2bf(sv[nf][1]);
      pw.z = f2bf(sv[nf][2]);
      pw.w = f2bf(sv[nf][3]);
      *(ushort4*)&Pq[w * 16 + l15][nf * 16 + quad * 4] = pw;
    }

    // rescale O: O regs hold qrow = quad*4+r -> broadcast alpha from lane qrow
    float al[4];
#pragma unroll
    for (int r = 0; r < 4; ++r) al[r] = __shfl(alpha, quad * 4 + r);
#pragma unroll
    for (int nfd = 0; nfd < 4; ++nfd)
#pragma unroll
      for (int r = 0; r < 4; ++r) Oa[nfd][r] *= al[r];

    // wave-local P write->read fence
    asm volatile("s_waitcnt lgkmcnt(0)" ::: "memory");

    // O += P V : A = P rows (m=qrow), B = Vt rows (n=d)
    const bf16x8 ap0 = *(const bf16x8*)&Pq[w * 16 + l15][quad * 8];
    const bf16x8 ap1 = *(const bf16x8*)&Pq[w * 16 + l15][32 + quad * 8];
#pragma unroll
    for (int nfd = 0; nfd < 4; ++nfd) {
      bf16x8 bv0 = *(const bf16x8*)&Vts[nfd * 16 + l15][quad * 8];
      bf16x8 bv1 = *(const bf16x8*)&Vts[nfd * 16 + l15][32 + quad * 8];
      Oa[nfd] = __builtin_amdgcn_mfma_f32_16x16x32_bf16(ap0, bv0, Oa[nfd], 0, 0, 0);
      Oa[nfd] = __builtin_amdgcn_mfma_f32_16x16x32_bf16(ap1, bv1, Oa[nfd], 0, 0, 0);
    }
  }

  // epilogue: O regs: lane l15 = d (within nfd tile), quad*4+r = qrow
#pragma unroll
  for (int r = 0; r < 4; ++r) {
    const float lr = __shfl(l_run, quad * 4 + r);
    const float rl = 1.0f / lr;
    const size_t base =
        ((size_t)b * T + q0 + w * 16 + quad * 4 + r) * (size_t)C + h * HD;
#pragma unroll
    for (int nfd = 0; nfd < 4; ++nfd)
      y[base + nfd * 16 + l15] = f2bf(Oa[nfd][r] * rl);
  }
}

}  // namespace

extern "C" void kernel_launch(void* const* d_in, const int* in_sizes, int n_in,
                              void* d_out, int out_size, void* d_ws,
                              size_t ws_size, hipStream_t stream) {
  const float* x      = (const float*)d_in[0];
  const float* W_attn = (const float*)d_in[1];
  const float* W_proj = (const float*)d_in[2];
  const int* indices  = (const int*)d_in[3];
  float* out = (float*)d_out;

  const size_t nM = (size_t)Bsz * T * C;  // 8M elements
  unsigned short* xb  = (unsigned short*)d_ws;
  unsigned short* wat = xb + nM;                       // [3C, C] transposed
  unsigned short* wpt = wat + (size_t)3 * C * C;       // [C, C] transposed
  unsigned short* qp  = wpt + (size_t)C * C;           // [B,H,T,HD]
  unsigned short* kp  = qp + nM;                       // [B,H,T,HD]
  unsigned short* vp  = kp + nM;                       // [B,H,HD,T] (transposed)
  unsigned short* yb  = vp + nM;                       // [B,T,C]

  f32_to_bf16_kernel<<<(int)(nM / 4 / 256), 256, 0, stream>>>(x, xb, (int)(nM / 4));
  transpose_bf16_kernel<<<dim3(3 * C / 32, C / 32), 256, 0, stream>>>(W_attn, wat, C, 3 * C);
  transpose_bf16_kernel<<<dim3(C / 32, C / 32), 256, 0, stream>>>(W_proj, wpt, C, C);
  gemm_bt<1><<<dim3(3 * C / 128, Bsz * T / 128), 256, 0, stream>>>(
      xb, wat, nullptr, qp, kp, vp, Bsz * T, 3 * C, C);
  rope_bf16<<<(Bsz * H * T) / 8, 256, 0, stream>>>(qp, kp, indices);
  flash_attn_mfma<<<dim3(T / 64, H, Bsz), 256, 0, stream>>>(qp, kp, vp, indices, yb);
  gemm_bt<0><<<dim3(C / 128, Bsz * T / 128), 256, 0, stream>>>(
      yb, wpt, out, nullptr, nullptr, nullptr, Bsz * T, C, C);
}

// Round 4
// 378.272 us; speedup vs baseline: 6.1421x; 1.0144x over previous
//
#include <hip/hip_runtime.h>
#include <math.h>

namespace {
constexpr int Bsz = 4;
constexpr int T   = 2048;
constexpr int C   = 1024;
constexpr int H   = 16;
constexpr int HD  = 64;

typedef short bf16x8 __attribute__((ext_vector_type(8)));
typedef float f32x4  __attribute__((ext_vector_type(4)));

#if defined(__has_builtin)
#if __has_builtin(__builtin_amdgcn_global_load_lds)
#define HAVE_GLL 1
typedef __attribute__((address_space(3))) unsigned int lds_u32_t;
typedef __attribute__((address_space(1))) unsigned int g_u32_t;
#define GLL16(gp, lp)                                                        \
  __builtin_amdgcn_global_load_lds((const g_u32_t*)(gp), (lds_u32_t*)(lp),   \
                                   16, 0, 0)
#endif
#if __has_builtin(__builtin_amdgcn_exp2f)
#define EXP2F(x) __builtin_amdgcn_exp2f(x)
#else
#define EXP2F(x) exp2f(x)
#endif
#endif
#ifndef EXP2F
#define EXP2F(x) exp2f(x)
#endif

__device__ __forceinline__ unsigned short f2bf(float f) {
  unsigned int u = __builtin_bit_cast(unsigned int, f);
  u += 0x7FFFu + ((u >> 16) & 1u);
  return (unsigned short)(u >> 16);
}
// pack two f32 -> bf16x2 (round-half-up via +0x8000, then byte-perm)
__device__ __forceinline__ unsigned int pack_bf(float a, float b) {
  unsigned int ua = __builtin_bit_cast(unsigned int, a) + 0x8000u;
  unsigned int ub = __builtin_bit_cast(unsigned int, b) + 0x8000u;
  return __builtin_amdgcn_perm(ub, ua, 0x07060302u);
}
__device__ __forceinline__ float bf2f(unsigned short s) {
  unsigned int u = ((unsigned int)s) << 16;
  return __builtin_bit_cast(float, u);
}

// ---------------- fp32 -> bf16 (same layout) ----------------
__global__ __launch_bounds__(256) void f32_to_bf16_kernel(
    const float* __restrict__ in, unsigned short* __restrict__ out, int n4) {
  int i = blockIdx.x * 256 + threadIdx.x;
  if (i < n4) {
    float4 v = ((const float4*)in)[i];
    ushort4 o;
    o.x = f2bf(v.x); o.y = f2bf(v.y); o.z = f2bf(v.z); o.w = f2bf(v.w);
    ((ushort4*)out)[i] = o;
  }
}

// ---------------- W [K,N] fp32 -> Wt [N,K] bf16 ----------------
__global__ __launch_bounds__(256) void transpose_bf16_kernel(
    const float* __restrict__ W, unsigned short* __restrict__ Wt, int K, int N) {
  __shared__ float tile[32][33];
  const int n0 = blockIdx.x * 32, k0 = blockIdx.y * 32;
  const int r = threadIdx.x >> 3, c4 = threadIdx.x & 7;
  float4 v = *(const float4*)(W + (size_t)(k0 + r) * N + n0 + c4 * 4);
  tile[r][c4 * 4 + 0] = v.x;
  tile[r][c4 * 4 + 1] = v.y;
  tile[r][c4 * 4 + 2] = v.z;
  tile[r][c4 * 4 + 3] = v.w;
  __syncthreads();
  ushort4 o;
  o.x = f2bf(tile[c4 * 4 + 0][r]);
  o.y = f2bf(tile[c4 * 4 + 1][r]);
  o.z = f2bf(tile[c4 * 4 + 2][r]);
  o.w = f2bf(tile[c4 * 4 + 3][r]);
  *(ushort4*)(Wt + (size_t)(n0 + r) * K + k0 + c4 * 4) = o;
}

// ---------------- bf16 MFMA GEMM: C[M,N] = A[M,K] @ Bt[N,K]^T ----------------
template <int MODE>
__global__ __launch_bounds__(256) void gemm_bt(
    const unsigned short* __restrict__ A, const unsigned short* __restrict__ Bt,
    float* __restrict__ Cout, unsigned short* __restrict__ qp,
    unsigned short* __restrict__ kp, unsigned short* __restrict__ vp,
    int M, int N, int K) {
  __shared__ __align__(16) unsigned short As[128 * 32];
  __shared__ __align__(16) unsigned short Bs[128 * 32];
  const int tid = threadIdx.x;
  const int lane = tid & 63, w = tid >> 6;
  const int wr = w & 1, wc = w >> 1;
  const int l15 = lane & 15, quad = lane >> 4;
  const int m0 = blockIdx.y * 128, n0 = blockIdx.x * 128;

  const int srow = lane >> 2;
  const int schunk = (lane & 3) * 8;
  const unsigned short* gA = A + (size_t)(m0 + w * 32 + srow) * K + schunk;
  const unsigned short* gB = Bt + (size_t)(n0 + w * 32 + srow) * K + schunk;
  unsigned short* lA0 = &As[(w * 32) * 32 + lane * 8];
  unsigned short* lA1 = &As[(w * 32 + 16) * 32 + lane * 8];
  unsigned short* lB0 = &Bs[(w * 32) * 32 + lane * 8];
  unsigned short* lB1 = &Bs[(w * 32 + 16) * 32 + lane * 8];

  f32x4 acc[4][4] = {};

  for (int k0 = 0; k0 < K; k0 += 32) {
    __syncthreads();
#ifdef HAVE_GLL
    GLL16(gA + k0, lA0);
    GLL16(gA + (size_t)16 * K + k0, lA1);
    GLL16(gB + k0, lB0);
    GLL16(gB + (size_t)16 * K + k0, lB1);
#else
    *(uint4*)lA0 = *(const uint4*)(gA + k0);
    *(uint4*)lA1 = *(const uint4*)(gA + (size_t)16 * K + k0);
    *(uint4*)lB0 = *(const uint4*)(gB + k0);
    *(uint4*)lB1 = *(const uint4*)(gB + (size_t)16 * K + k0);
#endif
    __syncthreads();

    bf16x8 af[4], bfr[4];
#pragma unroll
    for (int mf = 0; mf < 4; ++mf)
      af[mf] = *(const bf16x8*)&As[(wr * 64 + mf * 16 + l15) * 32 + quad * 8];
#pragma unroll
    for (int nf = 0; nf < 4; ++nf)
      bfr[nf] = *(const bf16x8*)&Bs[(wc * 64 + nf * 16 + l15) * 32 + quad * 8];
#pragma unroll
    for (int mf = 0; mf < 4; ++mf)
#pragma unroll
      for (int nf = 0; nf < 4; ++nf)
        acc[mf][nf] = __builtin_amdgcn_mfma_f32_16x16x32_bf16(
            af[mf], bfr[nf], acc[mf][nf], 0, 0, 0);
  }

#pragma unroll
  for (int mf = 0; mf < 4; ++mf) {
    const int row0 = m0 + wr * 64 + mf * 16 + quad * 4;
#pragma unroll
    for (int nf = 0; nf < 4; ++nf) {
      if (MODE == 0) {
#pragma unroll
        for (int r = 0; r < 4; ++r) {
          const int col = n0 + wc * 64 + nf * 16 + l15;
          Cout[(size_t)(row0 + r) * N + col] = acc[mf][nf][r];
        }
      } else {
        const int col = n0 + wc * 64 + nf * 16 + l15;
        const int which = col >> 10;
        const int rem = col & (C - 1);
        const int h = rem >> 6, hd = rem & 63;
        const int b = row0 >> 11, t0 = row0 & (T - 1);
        if (which == 2) {
          ushort4 pv;
          pv.x = f2bf(acc[mf][nf][0]);
          pv.y = f2bf(acc[mf][nf][1]);
          pv.z = f2bf(acc[mf][nf][2]);
          pv.w = f2bf(acc[mf][nf][3]);
          *(ushort4*)(vp + (((size_t)(b * H + h)) * HD + hd) * T + t0) = pv;
        } else {
          unsigned short* dst = which == 0 ? qp : kp;
#pragma unroll
          for (int r = 0; r < 4; ++r)
            dst[(((size_t)(b * H + h)) * T + t0 + r) * HD + hd] =
                f2bf(acc[mf][nf][r]);
        }
      }
    }
  }
}

// ---------------- RoPE in place on bf16 q,k [B,H,T,HD] ----------------
__global__ __launch_bounds__(256) void rope_bf16(unsigned short* __restrict__ q,
                                                 unsigned short* __restrict__ k,
                                                 const int* __restrict__ idx) {
  const size_t g = (size_t)blockIdx.x * 8 + (threadIdx.x >> 5);
  const int lane = threadIdx.x & 31;
  const int t = (int)(g & (size_t)(T - 1));
  const int bh = (int)(g >> 11);
  const int b = bh >> 4;
  const int pos = idx[b * T + t];
  const float inv = 1.0f / powf(10000.0f, (float)lane * (1.0f / 32.0f));
  float sn, cs;
  sincosf((float)pos * inv, &sn, &cs);
  const size_t base = g * (size_t)HD;
  float x1 = bf2f(q[base + lane]), x2 = bf2f(q[base + 32 + lane]);
  q[base + lane]      = f2bf(x1 * cs - x2 * sn);
  q[base + 32 + lane] = f2bf(x1 * sn + x2 * cs);
  x1 = bf2f(k[base + lane]);
  x2 = bf2f(k[base + 32 + lane]);
  k[base + lane]      = f2bf(x1 * cs - x2 * sn);
  k[base + 32 + lane] = f2bf(x1 * sn + x2 * cs);
}

// ---------------- MFMA flash attention, barrier-free ----------------
// Block 256 = 4 independent waves, each owns 32 q-rows. K-tile 64.
// All MFMA operand fragments loaded straight from global (K [t][d],
// V^T [d][t], Q [t][d]); only LDS use is the wave-private P round-trip.
// S^T = K·Q^T (lane = qrow); O^T = V^T·P^T (lane = qrow) -> softmax state
// stays per-lane, no broadcasts.
__global__ __launch_bounds__(256) void flash_attn_mfma(
    const unsigned short* __restrict__ q, const unsigned short* __restrict__ k,
    const unsigned short* __restrict__ vt, const int* __restrict__ idx,
    unsigned short* __restrict__ y) {
  __shared__ __align__(16) unsigned short Pq[128][72];  // wave-private 32-row slabs

  const int tid = threadIdx.x;
  const int lane = tid & 63, w = tid >> 6;
  const int l15 = lane & 15, quad = lane >> 4;
  const int h = blockIdx.y, b = blockIdx.z;
  // work-balance swizzle: per-CU q-tile sum constant under round-robin dispatch
  int qb = (blockIdx.x + ((b & 1) << 3)) & 15;
  if (b >= 2) qb = 15 - qb;
  const int qw = qb * 128 + w * 32;  // this wave's first q-row
  const size_t bh = (size_t)(b * H + h);
  const unsigned short* qg = q + bh * T * HD;
  const unsigned short* kg = k + bh * T * HD;
  const unsigned short* vg = vt + bh * HD * T;
  const int* idxb = idx + b * T;

  // Q B-frags (2 row-sets x 2 k-chunks), loaded once
  bf16x8 bq[2][2];
#pragma unroll
  for (int s = 0; s < 2; ++s)
#pragma unroll
    for (int c = 0; c < 2; ++c)
      bq[s][c] = *(const bf16x8*)(qg + (size_t)(qw + s * 16 + l15) * HD +
                                  c * 32 + quad * 8);

  int pq[2];
  pq[0] = idxb[qw + l15];
  pq[1] = idxb[qw + 16 + l15];
  int pqmin = min(pq[0], pq[1]);
#pragma unroll
  for (int off = 1; off < 16; off <<= 1)
    pqmin = min(pqmin, __shfl_xor(pqmin, off));

  float m2[2] = {-1e38f, -1e38f}, lr[2] = {0.0f, 0.0f};
  f32x4 Oa[2][4] = {};
  const float SC = 0.18033688f;  // 0.125 * log2(e)

  const int ktmax = (qw + 31) >> 6;
  for (int kt = 0; kt <= ktmax; ++kt) {
    const int k0 = kt * 64;

    // K A-frags: 4 key-tiles x 2 k-chunks
    bf16x8 ak[4][2];
#pragma unroll
    for (int nf = 0; nf < 4; ++nf)
#pragma unroll
      for (int c = 0; c < 2; ++c)
        ak[nf][c] = *(const bf16x8*)(kg + (size_t)(k0 + nf * 16 + l15) * HD +
                                     c * 32 + quad * 8);
    int4 pk4[4];
#pragma unroll
    for (int nf = 0; nf < 4; ++nf)
      pk4[nf] = *(const int4*)(idxb + k0 + nf * 16 + quad * 4);

    // S^T: lane = qrow, reg r of tile nf = key nf*16+quad*4+r
    float z[2][4][4];
#pragma unroll
    for (int s = 0; s < 2; ++s)
#pragma unroll
      for (int nf = 0; nf < 4; ++nf) {
        f32x4 acc = {};
        acc = __builtin_amdgcn_mfma_f32_16x16x32_bf16(ak[nf][0], bq[s][0], acc, 0, 0, 0);
        acc = __builtin_amdgcn_mfma_f32_16x16x32_bf16(ak[nf][1], bq[s][1], acc, 0, 0, 0);
#pragma unroll
        for (int r = 0; r < 4; ++r) z[s][nf][r] = acc[r] * SC;
      }

    // diagonal check: mask only if some key pos exceeds wave's min q pos
    int pkmax = max(max(max(pk4[0].x, pk4[0].y), max(pk4[0].z, pk4[0].w)),
                    max(max(pk4[1].x, pk4[1].y), max(pk4[1].z, pk4[1].w)));
    pkmax = max(pkmax, max(max(max(pk4[2].x, pk4[2].y), max(pk4[2].z, pk4[2].w)),
                           max(max(pk4[3].x, pk4[3].y), max(pk4[3].z, pk4[3].w))));
    pkmax = max(pkmax, __shfl_xor(pkmax, 16));
    pkmax = max(pkmax, __shfl_xor(pkmax, 32));
    if (pkmax > pqmin) {
#pragma unroll
      for (int s = 0; s < 2; ++s)
#pragma unroll
        for (int nf = 0; nf < 4; ++nf) {
          z[s][nf][0] = (pk4[nf].x > pq[s]) ? -3e38f : z[s][nf][0];
          z[s][nf][1] = (pk4[nf].y > pq[s]) ? -3e38f : z[s][nf][1];
          z[s][nf][2] = (pk4[nf].z > pq[s]) ? -3e38f : z[s][nf][2];
          z[s][nf][3] = (pk4[nf].w > pq[s]) ? -3e38f : z[s][nf][3];
        }
    }

    // online softmax per row-set (exp2 domain)
    float alpha[2];
#pragma unroll
    for (int s = 0; s < 2; ++s) {
      float mx = z[s][0][0];
#pragma unroll
      for (int nf = 0; nf < 4; ++nf)
#pragma unroll
        for (int r = 0; r < 4; ++r) mx = fmaxf(mx, z[s][nf][r]);
      mx = fmaxf(mx, __shfl_xor(mx, 16));
      mx = fmaxf(mx, __shfl_xor(mx, 32));
      const float mn = fmaxf(m2[s], mx);
      alpha[s] = EXP2F(m2[s] - mn);
      m2[s] = mn;
      float sum = 0.0f;
#pragma unroll
      for (int nf = 0; nf < 4; ++nf)
#pragma unroll
        for (int r = 0; r < 4; ++r) {
          float p = EXP2F(z[s][nf][r] - mn);
          z[s][nf][r] = p;
          sum += p;
        }
      sum += __shfl_xor(sum, 16);
      sum += __shfl_xor(sum, 32);
      lr[s] = lr[s] * alpha[s] + sum;
    }

    // P -> LDS (wave-private rows), packed 2-at-a-time
#pragma unroll
    for (int s = 0; s < 2; ++s)
#pragma unroll
      for (int nf = 0; nf < 4; ++nf) {
        uint2 pw;
        pw.x = pack_bf(z[s][nf][0], z[s][nf][1]);
        pw.y = pack_bf(z[s][nf][2], z[s][nf][3]);
        *(uint2*)&Pq[w * 32 + s * 16 + l15][nf * 16 + quad * 4] = pw;
      }

    // rescale O (per-lane, no broadcast needed: lane = qrow)
#pragma unroll
    for (int s = 0; s < 2; ++s)
#pragma unroll
      for (int nfd = 0; nfd < 4; ++nfd)
#pragma unroll
        for (int r = 0; r < 4; ++r) Oa[s][nfd][r] *= alpha[s];

    asm volatile("s_waitcnt lgkmcnt(0)" ::: "memory");

    // P B-frags from LDS
    bf16x8 bp[2][2];
#pragma unroll
    for (int s = 0; s < 2; ++s)
#pragma unroll
      for (int c = 0; c < 2; ++c)
        bp[s][c] = *(const bf16x8*)&Pq[w * 32 + s * 16 + l15][c * 32 + quad * 8];

    // O^T += V^T · P^T : A = V^T rows (m=d) straight from global
#pragma unroll
    for (int nfd = 0; nfd < 4; ++nfd) {
      const size_t vrow = (size_t)(nfd * 16 + l15) * T + k0;
      bf16x8 av0 = *(const bf16x8*)(vg + vrow + quad * 8);
      bf16x8 av1 = *(const bf16x8*)(vg + vrow + 32 + quad * 8);
#pragma unroll
      for (int s = 0; s < 2; ++s) {
        Oa[s][nfd] = __builtin_amdgcn_mfma_f32_16x16x32_bf16(av0, bp[s][0], Oa[s][nfd], 0, 0, 0);
        Oa[s][nfd] = __builtin_amdgcn_mfma_f32_16x16x32_bf16(av1, bp[s][1], Oa[s][nfd], 0, 0, 0);
      }
    }
  }

  // epilogue: lane = qrow (t), regs = d -> per-lane b64 stores
#pragma unroll
  for (int s = 0; s < 2; ++s) {
    const float rl = 1.0f / lr[s];
    const size_t base = ((size_t)b * T + qw + s * 16 + l15) * (size_t)C + h * HD;
#pragma unroll
    for (int nfd = 0; nfd < 4; ++nfd) {
      ushort4 o;
      o.x = f2bf(Oa[s][nfd][0] * rl);
      o.y = f2bf(Oa[s][nfd][1] * rl);
      o.z = f2bf(Oa[s][nfd][2] * rl);
      o.w = f2bf(Oa[s][nfd][3] * rl);
      *(ushort4*)(y + base + nfd * 16 + quad * 4) = o;
    }
  }
}

}  // namespace

extern "C" void kernel_launch(void* const* d_in, const int* in_sizes, int n_in,
                              void* d_out, int out_size, void* d_ws,
                              size_t ws_size, hipStream_t stream) {
  const float* x      = (const float*)d_in[0];
  const float* W_attn = (const float*)d_in[1];
  const float* W_proj = (const float*)d_in[2];
  const int* indices  = (const int*)d_in[3];
  float* out = (float*)d_out;

  const size_t nM = (size_t)Bsz * T * C;
  unsigned short* xb  = (unsigned short*)d_ws;
  unsigned short* wat = xb + nM;
  unsigned short* wpt = wat + (size_t)3 * C * C;
  unsigned short* qp  = wpt + (size_t)C * C;           // [B,H,T,HD]
  unsigned short* kp  = qp + nM;                       // [B,H,T,HD]
  unsigned short* vp  = kp + nM;                       // [B,H,HD,T]
  unsigned short* yb  = vp + nM;                       // [B,T,C]

  f32_to_bf16_kernel<<<(int)(nM / 4 / 256), 256, 0, stream>>>(x, xb, (int)(nM / 4));
  transpose_bf16_kernel<<<dim3(3 * C / 32, C / 32), 256, 0, stream>>>(W_attn, wat, C, 3 * C);
  transpose_bf16_kernel<<<dim3(C / 32, C / 32), 256, 0, stream>>>(W_proj, wpt, C, C);
  gemm_bt<1><<<dim3(3 * C / 128, Bsz * T / 128), 256, 0, stream>>>(
      xb, wat, nullptr, qp, kp, vp, Bsz * T, 3 * C, C);
  rope_bf16<<<(Bsz * H * T) / 8, 256, 0, stream>>>(qp, kp, indices);
  flash_attn_mfma<<<dim3(T / 128, H, Bsz), 256, 0, stream>>>(qp, kp, vp, indices, yb);
  gemm_bt<0><<<dim3(C / 128, Bsz * T / 128), 256, 0, stream>>>(
      yb, wpt, out, nullptr, nullptr, nullptr, Bsz * T, C, C);
}